// Round 4
// baseline (593.848 us; speedup 1.0000x reference)
//
#include <hip/hip_runtime.h>
#include <cmath>

#define WS  11
#define NX  160
#define NXY (NX*NX)         // 25600
#define NB  2
#define TH  16
#define TW  32
#define SH  26              // TH + 10 halo rows
#define SW  48              // staging cols: w0-8 .. w0+39
#define DC  32              // d outputs per block
#define NSL 42              // DC + 10 slices
#define MST 36              // mid row stride (pad for banks, mult of 4)
#define WST 36              // whb row stride

struct GaussW { float g[WS]; };

// Fused: per block = 16x32 (h,w) tile x 32 d-outputs. Stream 42 d-slices:
// stage x,y -> W-blur (5 fields on the fly) -> H-blur (field-split, 4-row
// register sliding, b128 reads) -> per-thread 55-reg ring along D -> SSIM.
__global__ __launch_bounds__(512, 4) void k_fused(const float* __restrict__ x,
                                                  const float* __restrict__ y,
                                                  float* __restrict__ partial,
                                                  GaussW gw) {
    __shared__ float sx[SH][SW];          // 4.99 KB
    __shared__ float sy[SH][SW];          // 4.99 KB
    __shared__ float mid[5][SH][MST];     // 18.7 KB  (W-blurred fields)
    __shared__ float whb[5][TH][WST];     // 11.5 KB  (W+H-blurred fields)
    __shared__ float wred[8];

    const int tid = threadIdx.x;
    const int w0 = blockIdx.x * TW;
    const int h0 = blockIdx.y * TH;
    const int b  = blockIdx.z / 5;
    const int d0 = (blockIdx.z % 5) * DC;
    const int vol = b * (NX * NXY);

    // stage role: 312 threads = 26 rows x 12 float4-cols
    const bool stager = tid < 312;
    const int sr = tid / 12, sq = tid % 12;
    const int gh = h0 - 5 + sr;
    const int gc = w0 - 8 + 4 * sq;
    const bool rowok = (unsigned)gh < (unsigned)NX;
    const bool allcolok = (gc >= 0) && (gc + 3 < NX);
    const int rowbase = vol + gh * NX + gc;        // + ds*NXY per slice

    // W-blur role: 208 threads = 26 rows x 8 col-quads
    const bool wb = tid < 208;
    const int wr  = tid >> 3;
    const int wc4 = (tid & 7) << 2;

    // H-blur role: 160 threads = 5 fields x 4 row-groups x 8 col-quads
    const bool hb = tid < 160;
    const int hf  = tid >> 5;
    const int hr0 = ((tid >> 3) & 3) << 2;
    const int hc4 = (tid & 7) << 2;

    // ring role: all 512, one (h,w) each
    const int pr = tid >> 5;      // 0..15
    const int pc = tid & 31;

    float win[5][WS];
    #pragma unroll
    for (int f = 0; f < 5; ++f)
        #pragma unroll
        for (int i = 0; i < WS; ++i) win[f][i] = 0.f;
    float acc = 0.f;

    auto STAGE_LOAD = [&](int ds, float4& lx, float4& ly) {
        const int base = rowbase + ds * NXY;
        if (rowok && allcolok) {
            lx = *(const float4*)(x + base);
            ly = *(const float4*)(y + base);
        } else {
            float vx[4] = {0,0,0,0}, vy[4] = {0,0,0,0};
            if (rowok) {
                #pragma unroll
                for (int e = 0; e < 4; ++e)
                    if ((unsigned)(gc + e) < (unsigned)NX) {
                        vx[e] = x[base + e]; vy[e] = y[base + e];
                    }
            }
            lx = make_float4(vx[0], vx[1], vx[2], vx[3]);
            ly = make_float4(vy[0], vy[1], vy[2], vy[3]);
        }
    };
    auto STAGE_WRITE = [&](const float4& lx, const float4& ly) {
        *(float4*)&sx[sr][4 * sq] = lx;
        *(float4*)&sy[sr][4 * sq] = ly;
    };

    auto WBLUR = [&]() {
        if (!wb) return;
        float wx[16], wy[16];
        #pragma unroll
        for (int m = 0; m < 8; ++m) {
            const float2 xv = *(const float2*)&sx[wr][wc4 + 2 + 2 * m];
            const float2 yv = *(const float2*)&sy[wr][wc4 + 2 + 2 * m];
            wx[2*m] = xv.x; wx[2*m+1] = xv.y;
            wy[2*m] = yv.x; wy[2*m+1] = yv.y;
        }
        float a0[4] = {0,0,0,0}, a1[4] = {0,0,0,0}, a2[4] = {0,0,0,0},
              a3[4] = {0,0,0,0}, a4[4] = {0,0,0,0};
        #pragma unroll
        for (int k = 0; k < WS; ++k) {
            const float gk = gw.g[k];
            #pragma unroll
            for (int j = 0; j < 4; ++j) {
                const float xv = wx[j + k + 1];   // staged col c+3+k for output col c
                const float yv = wy[j + k + 1];
                const float t0 = gk * xv, t1 = gk * yv;
                a0[j] += t0;       a1[j] += t1;
                a2[j] += t0 * xv;  a3[j] += t1 * yv;  a4[j] += t0 * yv;
            }
        }
        *(float4*)&mid[0][wr][wc4] = make_float4(a0[0], a0[1], a0[2], a0[3]);
        *(float4*)&mid[1][wr][wc4] = make_float4(a1[0], a1[1], a1[2], a1[3]);
        *(float4*)&mid[2][wr][wc4] = make_float4(a2[0], a2[1], a2[2], a2[3]);
        *(float4*)&mid[3][wr][wc4] = make_float4(a3[0], a3[1], a3[2], a3[3]);
        *(float4*)&mid[4][wr][wc4] = make_float4(a4[0], a4[1], a4[2], a4[3]);
    };

    auto HBLUR = [&]() {
        if (!hb) return;
        float4 o0 = {0,0,0,0}, o1 = {0,0,0,0}, o2 = {0,0,0,0}, o3 = {0,0,0,0};
        #pragma unroll
        for (int k2 = 0; k2 < 14; ++k2) {
            const float4 v = *(const float4*)&mid[hf][hr0 + k2][hc4];
            if (k2 <= 10) { const float g = gw.g[k2];
                o0.x += g*v.x; o0.y += g*v.y; o0.z += g*v.z; o0.w += g*v.w; }
            if (k2 >= 1 && k2 <= 11) { const float g = gw.g[k2-1];
                o1.x += g*v.x; o1.y += g*v.y; o1.z += g*v.z; o1.w += g*v.w; }
            if (k2 >= 2 && k2 <= 12) { const float g = gw.g[k2-2];
                o2.x += g*v.x; o2.y += g*v.y; o2.z += g*v.z; o2.w += g*v.w; }
            if (k2 >= 3) { const float g = gw.g[k2-3];
                o3.x += g*v.x; o3.y += g*v.y; o3.z += g*v.z; o3.w += g*v.w; }
        }
        *(float4*)&whb[hf][hr0 + 0][hc4] = o0;
        *(float4*)&whb[hf][hr0 + 1][hc4] = o1;
        *(float4*)&whb[hf][hr0 + 2][hc4] = o2;
        *(float4*)&whb[hf][hr0 + 3][hc4] = o3;
    };

    // ---- prologue: produce whb for slice s=0 ----
    {
        const int ds = d0 - 5;
        const bool v0 = (unsigned)ds < (unsigned)NX;
        if (v0 && stager) { float4 lx, ly; STAGE_LOAD(ds, lx, ly); STAGE_WRITE(lx, ly); }
        __syncthreads();
        if (v0) WBLUR();
        __syncthreads();
        if (v0) HBLUR();
        __syncthreads();
    }

    // ---- main loop over 42 slices ----
    for (int s = 0; s < NSL; ++s) {
        const int ds  = d0 - 5 + s;
        const bool vs  = (unsigned)ds < (unsigned)NX;
        const bool vs1 = (s + 1 < NSL) && ((unsigned)(ds + 1) < (unsigned)NX);

        // region A: issue next-slice loads early (T14), ring-push(s), write late
        float4 lx, ly;
        if (vs1 && stager) STAGE_LOAD(ds + 1, lx, ly);

        float v[5];
        if (vs) {
            #pragma unroll
            for (int f = 0; f < 5; ++f) v[f] = whb[f][pr][pc];
        } else {
            #pragma unroll
            for (int f = 0; f < 5; ++f) v[f] = 0.f;
        }
        #pragma unroll
        for (int f = 0; f < 5; ++f) {
            #pragma unroll
            for (int i = 0; i < WS - 1; ++i) win[f][i] = win[f][i + 1];
            win[f][WS - 1] = v[f];
        }
        if (s >= 10) {   // output d = d0 + s - 10, window = slices s-10..s
            float m[5];
            #pragma unroll
            for (int f = 0; f < 5; ++f) {
                float t = 0.f;
                #pragma unroll
                for (int i = 0; i < WS; ++i) t += gw.g[i] * win[f][i];
                m[f] = t;
            }
            const float mux = m[0], muy = m[1];
            const float mux2 = mux * mux, muy2 = muy * muy, muxy = mux * muy;
            const float sxx = m[2] - mux2, syy = m[3] - muy2, sxy = m[4] - muxy;
            const float num = (2.f * muxy + 1.0e-4f) * (2.f * sxy + 9.0e-4f);
            const float den = (mux2 + muy2 + 1.0e-4f) * (sxx + syy + 9.0e-4f);
            acc += num / den;
        }
        if (vs1 && stager) STAGE_WRITE(lx, ly);
        __syncthreads();

        if (vs1) WBLUR();
        __syncthreads();
        if (vs1) HBLUR();
        __syncthreads();
    }

    // ---- block reduce ----
    #pragma unroll
    for (int off = 32; off > 0; off >>= 1) acc += __shfl_down(acc, off, 64);
    if ((tid & 63) == 0) wred[tid >> 6] = acc;
    __syncthreads();
    if (tid == 0) {
        float s8 = 0.f;
        #pragma unroll
        for (int wv = 0; wv < 8; ++wv) s8 += wred[wv];
        partial[(blockIdx.z * gridDim.y + blockIdx.y) * gridDim.x + blockIdx.x] = s8;
    }
}

__global__ __launch_bounds__(256) void k_red(const float* __restrict__ partial,
                                             int n, float* __restrict__ out) {
    double s = 0.0;
    for (int i = threadIdx.x; i < n; i += 256) s += (double)partial[i];
    __shared__ double sd[256];
    sd[threadIdx.x] = s;
    __syncthreads();
    for (int st = 128; st > 0; st >>= 1) {
        if (threadIdx.x < st) sd[threadIdx.x] += sd[threadIdx.x + st];
        __syncthreads();
    }
    if (threadIdx.x == 0)
        out[0] = (float)(sd[0] / (double)((long long)NB * NX * NX * NX));
}

extern "C" void kernel_launch(void* const* d_in, const int* in_sizes, int n_in,
                              void* d_out, int out_size, void* d_ws, size_t ws_size,
                              hipStream_t stream) {
    const float* x = (const float*)d_in[0];
    const float* y = (const float*)d_in[1];
    float* partial = (float*)d_ws;

    GaussW gw;
    {
        float tmp[WS]; float s = 0.f;
        for (int i = 0; i < WS; ++i) {
            const double e = exp(-(double)((i - 5) * (i - 5)) / 4.5);
            tmp[i] = (float)e; s += tmp[i];
        }
        for (int i = 0; i < WS; ++i) gw.g[i] = tmp[i] / s;
    }

    dim3 grid(NX / TW, NX / TH, NB * (NX / DC));   // (5,10,10) = 500 blocks
    k_fused<<<grid, 512, 0, stream>>>(x, y, partial, gw);
    k_red<<<1, 256, 0, stream>>>(partial, 500, (float*)d_out);
}

// Round 5
// 183.848 us; speedup vs baseline: 3.2301x; 3.2301x over previous
//
#include <hip/hip_runtime.h>
#include <cmath>

#define WS  11
#define NX  160
#define NXY (NX*NX)         // 25600
#define NB  2
#define TH  16
#define TW  32
#define SH  26              // TH + 10 halo rows
#define SW  48              // staging cols: w0-8 .. w0+39
#define DC  32              // d outputs per block
#define NSL 42              // DC + 10 slices
#define MST 36              // mid row stride (pad for banks, mult of 4)
#define WST 36              // whb row stride

struct GaussW { float g[WS]; };

// Fused: per block = 16x32 (h,w) tile x 32 d-outputs. Stream 42 d-slices:
// stage x,y -> W-blur (5 fields on the fly) -> H-blur (field-split, 4-row
// register sliding, b128 reads) -> per-thread 55-reg ring along D -> SSIM.
// launch_bounds(512,2): 2 blocks/CU -> 128 VGPR cap (4,=64 VGPR, spilled the
// 55-reg ring to scratch: 2.4 GB HBM scratch traffic, 594 us).
__global__ __launch_bounds__(512, 2) void k_fused(const float* __restrict__ x,
                                                  const float* __restrict__ y,
                                                  float* __restrict__ partial,
                                                  GaussW gw) {
    __shared__ float sx[SH][SW];          // 4.99 KB
    __shared__ float sy[SH][SW];          // 4.99 KB
    __shared__ float mid[5][SH][MST];     // 18.7 KB  (W-blurred fields)
    __shared__ float whb[5][TH][WST];     // 11.5 KB  (W+H-blurred fields)
    __shared__ float wred[8];

    const int tid = threadIdx.x;
    const int w0 = blockIdx.x * TW;
    const int h0 = blockIdx.y * TH;
    const int b  = blockIdx.z / 5;
    const int d0 = (blockIdx.z % 5) * DC;
    const int vol = b * (NX * NXY);

    // stage role: 312 threads = 26 rows x 12 float4-cols
    const bool stager = tid < 312;
    const int sr = tid / 12, sq = tid % 12;
    const int gh = h0 - 5 + sr;
    const int gc = w0 - 8 + 4 * sq;
    const bool rowok = (unsigned)gh < (unsigned)NX;
    const bool allcolok = (gc >= 0) && (gc + 3 < NX);
    const int rowbase = vol + gh * NX + gc;        // + ds*NXY per slice

    // W-blur role: 208 threads = 26 rows x 8 col-quads
    const bool wb = tid < 208;
    const int wr  = tid >> 3;
    const int wc4 = (tid & 7) << 2;

    // H-blur role: 160 threads = 5 fields x 4 row-groups x 8 col-quads
    const bool hb = tid < 160;
    const int hf  = tid >> 5;
    const int hr0 = ((tid >> 3) & 3) << 2;
    const int hc4 = (tid & 7) << 2;

    // ring role: all 512, one (h,w) each
    const int pr = tid >> 5;      // 0..15
    const int pc = tid & 31;

    float win[5][WS];
    #pragma unroll
    for (int f = 0; f < 5; ++f)
        #pragma unroll
        for (int i = 0; i < WS; ++i) win[f][i] = 0.f;
    float acc = 0.f;

    auto STAGE_LOAD = [&](int ds, float4& lx, float4& ly) {
        const int base = rowbase + ds * NXY;
        if (rowok && allcolok) {
            lx = *(const float4*)(x + base);
            ly = *(const float4*)(y + base);
        } else {
            float vx[4] = {0,0,0,0}, vy[4] = {0,0,0,0};
            if (rowok) {
                #pragma unroll
                for (int e = 0; e < 4; ++e)
                    if ((unsigned)(gc + e) < (unsigned)NX) {
                        vx[e] = x[base + e]; vy[e] = y[base + e];
                    }
            }
            lx = make_float4(vx[0], vx[1], vx[2], vx[3]);
            ly = make_float4(vy[0], vy[1], vy[2], vy[3]);
        }
    };
    auto STAGE_WRITE = [&](const float4& lx, const float4& ly) {
        *(float4*)&sx[sr][4 * sq] = lx;
        *(float4*)&sy[sr][4 * sq] = ly;
    };

    auto WBLUR = [&]() {
        if (!wb) return;
        float wx[16], wy[16];
        #pragma unroll
        for (int m = 0; m < 8; ++m) {
            const float2 xv = *(const float2*)&sx[wr][wc4 + 2 + 2 * m];
            const float2 yv = *(const float2*)&sy[wr][wc4 + 2 + 2 * m];
            wx[2*m] = xv.x; wx[2*m+1] = xv.y;
            wy[2*m] = yv.x; wy[2*m+1] = yv.y;
        }
        float a0[4] = {0,0,0,0}, a1[4] = {0,0,0,0}, a2[4] = {0,0,0,0},
              a3[4] = {0,0,0,0}, a4[4] = {0,0,0,0};
        #pragma unroll
        for (int k = 0; k < WS; ++k) {
            const float gk = gw.g[k];
            #pragma unroll
            for (int j = 0; j < 4; ++j) {
                const float xv = wx[j + k + 1];   // staged col c+3+k for output col c
                const float yv = wy[j + k + 1];
                const float t0 = gk * xv, t1 = gk * yv;
                a0[j] += t0;       a1[j] += t1;
                a2[j] += t0 * xv;  a3[j] += t1 * yv;  a4[j] += t0 * yv;
            }
        }
        *(float4*)&mid[0][wr][wc4] = make_float4(a0[0], a0[1], a0[2], a0[3]);
        *(float4*)&mid[1][wr][wc4] = make_float4(a1[0], a1[1], a1[2], a1[3]);
        *(float4*)&mid[2][wr][wc4] = make_float4(a2[0], a2[1], a2[2], a2[3]);
        *(float4*)&mid[3][wr][wc4] = make_float4(a3[0], a3[1], a3[2], a3[3]);
        *(float4*)&mid[4][wr][wc4] = make_float4(a4[0], a4[1], a4[2], a4[3]);
    };

    auto HBLUR = [&]() {
        if (!hb) return;
        float4 o0 = {0,0,0,0}, o1 = {0,0,0,0}, o2 = {0,0,0,0}, o3 = {0,0,0,0};
        #pragma unroll
        for (int k2 = 0; k2 < 14; ++k2) {
            const float4 v = *(const float4*)&mid[hf][hr0 + k2][hc4];
            if (k2 <= 10) { const float g = gw.g[k2];
                o0.x += g*v.x; o0.y += g*v.y; o0.z += g*v.z; o0.w += g*v.w; }
            if (k2 >= 1 && k2 <= 11) { const float g = gw.g[k2-1];
                o1.x += g*v.x; o1.y += g*v.y; o1.z += g*v.z; o1.w += g*v.w; }
            if (k2 >= 2 && k2 <= 12) { const float g = gw.g[k2-2];
                o2.x += g*v.x; o2.y += g*v.y; o2.z += g*v.z; o2.w += g*v.w; }
            if (k2 >= 3) { const float g = gw.g[k2-3];
                o3.x += g*v.x; o3.y += g*v.y; o3.z += g*v.z; o3.w += g*v.w; }
        }
        *(float4*)&whb[hf][hr0 + 0][hc4] = o0;
        *(float4*)&whb[hf][hr0 + 1][hc4] = o1;
        *(float4*)&whb[hf][hr0 + 2][hc4] = o2;
        *(float4*)&whb[hf][hr0 + 3][hc4] = o3;
    };

    // ---- prologue: produce whb for slice s=0 ----
    {
        const int ds = d0 - 5;
        const bool v0 = (unsigned)ds < (unsigned)NX;
        if (v0 && stager) { float4 lx, ly; STAGE_LOAD(ds, lx, ly); STAGE_WRITE(lx, ly); }
        __syncthreads();
        if (v0) WBLUR();
        __syncthreads();
        if (v0) HBLUR();
        __syncthreads();
    }

    // ---- main loop over 42 slices ----
    for (int s = 0; s < NSL; ++s) {
        const int ds  = d0 - 5 + s;
        const bool vs  = (unsigned)ds < (unsigned)NX;
        const bool vs1 = (s + 1 < NSL) && ((unsigned)(ds + 1) < (unsigned)NX);

        // region A: issue next-slice loads early (T14), ring-push(s), write late
        float4 lx, ly;
        if (vs1 && stager) STAGE_LOAD(ds + 1, lx, ly);

        float v[5];
        if (vs) {
            #pragma unroll
            for (int f = 0; f < 5; ++f) v[f] = whb[f][pr][pc];
        } else {
            #pragma unroll
            for (int f = 0; f < 5; ++f) v[f] = 0.f;
        }
        #pragma unroll
        for (int f = 0; f < 5; ++f) {
            #pragma unroll
            for (int i = 0; i < WS - 1; ++i) win[f][i] = win[f][i + 1];
            win[f][WS - 1] = v[f];
        }
        if (s >= 10) {   // output d = d0 + s - 10, window = slices s-10..s
            float m[5];
            #pragma unroll
            for (int f = 0; f < 5; ++f) {
                float t = 0.f;
                #pragma unroll
                for (int i = 0; i < WS; ++i) t += gw.g[i] * win[f][i];
                m[f] = t;
            }
            const float mux = m[0], muy = m[1];
            const float mux2 = mux * mux, muy2 = muy * muy, muxy = mux * muy;
            const float sxx = m[2] - mux2, syy = m[3] - muy2, sxy = m[4] - muxy;
            const float num = (2.f * muxy + 1.0e-4f) * (2.f * sxy + 9.0e-4f);
            const float den = (mux2 + muy2 + 1.0e-4f) * (sxx + syy + 9.0e-4f);
            acc += num / den;
        }
        if (vs1 && stager) STAGE_WRITE(lx, ly);
        __syncthreads();

        if (vs1) WBLUR();
        __syncthreads();
        if (vs1) HBLUR();
        __syncthreads();
    }

    // ---- block reduce ----
    #pragma unroll
    for (int off = 32; off > 0; off >>= 1) acc += __shfl_down(acc, off, 64);
    if ((tid & 63) == 0) wred[tid >> 6] = acc;
    __syncthreads();
    if (tid == 0) {
        float s8 = 0.f;
        #pragma unroll
        for (int wv = 0; wv < 8; ++wv) s8 += wred[wv];
        partial[(blockIdx.z * gridDim.y + blockIdx.y) * gridDim.x + blockIdx.x] = s8;
    }
}

__global__ __launch_bounds__(256) void k_red(const float* __restrict__ partial,
                                             int n, float* __restrict__ out) {
    double s = 0.0;
    for (int i = threadIdx.x; i < n; i += 256) s += (double)partial[i];
    __shared__ double sd[256];
    sd[threadIdx.x] = s;
    __syncthreads();
    for (int st = 128; st > 0; st >>= 1) {
        if (threadIdx.x < st) sd[threadIdx.x] += sd[threadIdx.x + st];
        __syncthreads();
    }
    if (threadIdx.x == 0)
        out[0] = (float)(sd[0] / (double)((long long)NB * NX * NX * NX));
}

extern "C" void kernel_launch(void* const* d_in, const int* in_sizes, int n_in,
                              void* d_out, int out_size, void* d_ws, size_t ws_size,
                              hipStream_t stream) {
    const float* x = (const float*)d_in[0];
    const float* y = (const float*)d_in[1];
    float* partial = (float*)d_ws;

    GaussW gw;
    {
        float tmp[WS]; float s = 0.f;
        for (int i = 0; i < WS; ++i) {
            const double e = exp(-(double)((i - 5) * (i - 5)) / 4.5);
            tmp[i] = (float)e; s += tmp[i];
        }
        for (int i = 0; i < WS; ++i) gw.g[i] = tmp[i] / s;
    }

    dim3 grid(NX / TW, NX / TH, NB * (NX / DC));   // (5,10,10) = 500 blocks
    k_fused<<<grid, 512, 0, stream>>>(x, y, partial, gw);
    k_red<<<1, 256, 0, stream>>>(partial, 500, (float*)d_out);
}

// Round 6
// 115.936 us; speedup vs baseline: 5.1222x; 1.5858x over previous
//
#include <hip/hip_runtime.h>
#include <cmath>

#define WS  11
#define NX  160
#define NXY (NX*NX)
#define NB  2
#define TH  16
#define TW  32
#define MH  26              // mid rows = TH + 10
#define MST 36              // mid row stride (b128-aligned, conflict-free)
#define DCHUNK 40
#define PLANE_I 8192000     // NB*NX*NX*NX

struct GaussW { float g[WS]; };

// k_wh: per (b,d) slice, 16x32 tile. Phase 1: W-blur straight from global
// (5 float4 loads per array per thread -> 20-col register window), 5 fields on
// the fly, write mid[5][26][36] to LDS. Barrier. Phase 2: H-blur (4 rows x
// 4 cols x 1 field per thread, b128 reads), store planar A[f].
__global__ __launch_bounds__(256, 4) void k_wh(const float* __restrict__ x,
                                               const float* __restrict__ y,
                                               float* __restrict__ A,
                                               GaussW gw) {
    __shared__ float mid[5][MH][MST];     // 18.72 KB

    const int tid = threadIdx.x;
    const int b  = blockIdx.z / NX;
    const int d  = blockIdx.z % NX;
    const int h0 = blockIdx.y * TH;
    const int w0 = blockIdx.x * TW;
    const int slice = (b * NX + d) * NXY;

    // ---- Phase 1: W-blur, 208 threads = 26 rows x 8 col-quads ----
    if (tid < 208) {
        const int wr = tid >> 3;          // 0..25
        const int wq = tid & 7;           // 0..7
        const int gh = h0 - 5 + wr;
        const bool rowok = (unsigned)gh < (unsigned)NX;
        const int c0 = w0 + 4 * wq - 8;   // first loaded col (float4-aligned)
        const int rbase = slice + gh * NX;

        float wx[20], wy[20];
        #pragma unroll
        for (int i = 0; i < 5; ++i) {
            const int ci = c0 + 4 * i;
            float4 xv = {0,0,0,0}, yv = {0,0,0,0};
            if (rowok) {
                if (ci >= 0 && ci + 3 < NX) {
                    xv = *(const float4*)(x + rbase + ci);
                    yv = *(const float4*)(y + rbase + ci);
                } else {
                    float ex[4] = {0,0,0,0}, ey[4] = {0,0,0,0};
                    #pragma unroll
                    for (int e = 0; e < 4; ++e)
                        if ((unsigned)(ci + e) < (unsigned)NX) {
                            ex[e] = x[rbase + ci + e];
                            ey[e] = y[rbase + ci + e];
                        }
                    xv = make_float4(ex[0], ex[1], ex[2], ex[3]);
                    yv = make_float4(ey[0], ey[1], ey[2], ey[3]);
                }
            }
            wx[4*i] = xv.x; wx[4*i+1] = xv.y; wx[4*i+2] = xv.z; wx[4*i+3] = xv.w;
            wy[4*i] = yv.x; wy[4*i+1] = yv.y; wy[4*i+2] = yv.z; wy[4*i+3] = yv.w;
        }
        // output col jj (global w0+4wq+jj): window = wx[3+jj+k-? ]:
        // wx[m] = global col c0+m = w0+4wq-8+m; need w0+4wq+jj-5+k -> m = 3+jj+k
        float a0[4] = {0,0,0,0}, a1[4] = {0,0,0,0}, a2[4] = {0,0,0,0},
              a3[4] = {0,0,0,0}, a4[4] = {0,0,0,0};
        #pragma unroll
        for (int k = 0; k < WS; ++k) {
            const float gk = gw.g[k];
            #pragma unroll
            for (int jj = 0; jj < 4; ++jj) {
                const float xv = wx[3 + jj + k];
                const float yv = wy[3 + jj + k];
                const float t0 = gk * xv, t1 = gk * yv;
                a0[jj] += t0;       a1[jj] += t1;
                a2[jj] += t0 * xv;  a3[jj] += t1 * yv;  a4[jj] += t0 * yv;
            }
        }
        *(float4*)&mid[0][wr][4*wq] = make_float4(a0[0], a0[1], a0[2], a0[3]);
        *(float4*)&mid[1][wr][4*wq] = make_float4(a1[0], a1[1], a1[2], a1[3]);
        *(float4*)&mid[2][wr][4*wq] = make_float4(a2[0], a2[1], a2[2], a2[3]);
        *(float4*)&mid[3][wr][4*wq] = make_float4(a3[0], a3[1], a3[2], a3[3]);
        *(float4*)&mid[4][wr][4*wq] = make_float4(a4[0], a4[1], a4[2], a4[3]);
    }
    __syncthreads();

    // ---- Phase 2: H-blur, 160 threads = 5 fields x 4 row-groups x 8 col-quads ----
    if (tid < 160) {
        const int hf  = tid >> 5;
        const int hr0 = ((tid >> 3) & 3) << 2;
        const int hq4 = (tid & 7) << 2;
        float4 o0 = {0,0,0,0}, o1 = {0,0,0,0}, o2 = {0,0,0,0}, o3 = {0,0,0,0};
        #pragma unroll
        for (int k2 = 0; k2 < 14; ++k2) {
            const float4 v = *(const float4*)&mid[hf][hr0 + k2][hq4];
            if (k2 <= 10) { const float g = gw.g[k2];
                o0.x += g*v.x; o0.y += g*v.y; o0.z += g*v.z; o0.w += g*v.w; }
            if (k2 >= 1 && k2 <= 11) { const float g = gw.g[k2-1];
                o1.x += g*v.x; o1.y += g*v.y; o1.z += g*v.z; o1.w += g*v.w; }
            if (k2 >= 2 && k2 <= 12) { const float g = gw.g[k2-2];
                o2.x += g*v.x; o2.y += g*v.y; o2.z += g*v.z; o2.w += g*v.w; }
            if (k2 >= 3) { const float g = gw.g[k2-3];
                o3.x += g*v.x; o3.y += g*v.y; o3.z += g*v.z; o3.w += g*v.w; }
        }
        const int obase = hf * PLANE_I + slice + (h0 + hr0) * NX + w0 + hq4;
        *(float4*)(A + obase)          = o0;
        *(float4*)(A + obase + NX)     = o1;
        *(float4*)(A + obase + 2*NX)   = o2;
        *(float4*)(A + obase + 3*NX)   = o3;
    }
}

// k_d: D-blur with register sliding window + SSIM + block reduce. (proven)
__global__ __launch_bounds__(256) void k_d(const float* __restrict__ A,
                                           float* __restrict__ partial,
                                           GaussW gw) {
    const int tid = threadIdx.x;
    const long long gidx = (long long)blockIdx.x * 256 + tid;
    const int NCOL = NB * NX * NX;
    const int chunk = (int)(gidx / NCOL);
    const int col   = (int)(gidx % NCOL);
    const int b  = col / (NX * NX);
    const int hw = col % (NX * NX);
    const int base = b * (NX * NXY) + hw;
    const int d0 = chunk * DCHUNK;

    float win[5][WS];
    #pragma unroll
    for (int i = 0; i < WS; ++i) {
        const int di = d0 - 5 + i;
        const bool ok = (di >= 0 && di < NX);
        const int o = base + (ok ? di : 0) * NXY;
        #pragma unroll
        for (int f = 0; f < 5; ++f)
            win[f][i] = ok ? A[f * PLANE_I + o] : 0.f;
    }

    float acc = 0.f;
    for (int dd = 0; dd < DCHUNK; ++dd) {
        float m[5];
        #pragma unroll
        for (int f = 0; f < 5; ++f) {
            float s = 0.f;
            #pragma unroll
            for (int i = 0; i < WS; ++i) s += gw.g[i] * win[f][i];
            m[f] = s;
        }
        const float mux = m[0], muy = m[1];
        const float mux2 = mux * mux, muy2 = muy * muy, muxy = mux * muy;
        const float sxx = m[2] - mux2, syy = m[3] - muy2, sxy = m[4] - muxy;
        const float num = (2.f * muxy + 1.0e-4f) * (2.f * sxy + 9.0e-4f);
        const float den = (mux2 + muy2 + 1.0e-4f) * (sxx + syy + 9.0e-4f);
        acc += num / den;

        const int dn = d0 + dd + 6;
        const bool ok = (dn < NX);
        const int o = base + (ok ? dn : 0) * NXY;
        #pragma unroll
        for (int f = 0; f < 5; ++f) {
            #pragma unroll
            for (int i = 0; i < WS - 1; ++i) win[f][i] = win[f][i + 1];
            win[f][WS - 1] = ok ? A[f * PLANE_I + o] : 0.f;
        }
    }

    for (int off = 32; off > 0; off >>= 1) acc += __shfl_down(acc, off, 64);
    __shared__ float wsum[4];
    if ((tid & 63) == 0) wsum[tid >> 6] = acc;
    __syncthreads();
    if (tid == 0) partial[blockIdx.x] = wsum[0] + wsum[1] + wsum[2] + wsum[3];
}

__global__ __launch_bounds__(256) void k_red(const float* __restrict__ partial,
                                             int n, float* __restrict__ out) {
    double s = 0.0;
    for (int i = threadIdx.x; i < n; i += 256) s += (double)partial[i];
    __shared__ double sd[256];
    sd[threadIdx.x] = s;
    __syncthreads();
    for (int st = 128; st > 0; st >>= 1) {
        if (threadIdx.x < st) sd[threadIdx.x] += sd[threadIdx.x + st];
        __syncthreads();
    }
    if (threadIdx.x == 0)
        out[0] = (float)(sd[0] / (double)((long long)NB * NX * NXY));
}

extern "C" void kernel_launch(void* const* d_in, const int* in_sizes, int n_in,
                              void* d_out, int out_size, void* d_ws, size_t ws_size,
                              hipStream_t stream) {
    const float* x = (const float*)d_in[0];
    const float* y = (const float*)d_in[1];
    float* A = (float*)d_ws;
    float* partial = (float*)((char*)d_ws + (size_t)5 * PLANE_I * sizeof(float));

    GaussW gw;
    {
        float tmp[WS]; float s = 0.f;
        for (int i = 0; i < WS; ++i) {
            const double e = exp(-(double)((i - 5) * (i - 5)) / 4.5);
            tmp[i] = (float)e; s += tmp[i];
        }
        for (int i = 0; i < WS; ++i) gw.g[i] = tmp[i] / s;
    }

    dim3 g1(NX / TW, NX / TH, NB * NX);   // (5,10,320) = 16000 blocks
    k_wh<<<g1, 256, 0, stream>>>(x, y, A, gw);

    const int nblk2 = (NB * NX * NX * (NX / DCHUNK)) / 256;  // 800
    k_d<<<nblk2, 256, 0, stream>>>(A, partial, gw);

    k_red<<<1, 256, 0, stream>>>(partial, nblk2, (float*)d_out);
}